// Round 6
// baseline (398.441 us; speedup 1.0000x reference)
//
#include <hip/hip_runtime.h>

typedef unsigned short u16;
typedef __attribute__((ext_vector_type(8))) short bf16x8;
typedef __attribute__((ext_vector_type(8))) unsigned short u16x8;
typedef __attribute__((ext_vector_type(4))) float f32x4;
typedef __attribute__((ext_vector_type(2))) float f32x2;

#define HI 256
#define WI 256
#define CI 64
#define OC 128
#define HO 128
#define WO 128
#define NB 8
#define KC 576
#define KCP 584          // +8 pad to break LDS bank stride
#define TW 32            // k_main pixel tile (r2-passing structure)

static __device__ __forceinline__ u16 f2bf(float f) {   // RNE
    union { float f; unsigned u; } v; v.f = f;
    return (u16)((v.u + 0x7FFFu + ((v.u >> 16) & 1u)) >> 16);
}
// unpack dword of 2 bf16 -> f32x2 (x = low u16 = element j, y = high u16 = element j+1)
static __device__ __forceinline__ f32x2 unpack2(unsigned d) {
    union { unsigned u; float f; } lo, hi;
    lo.u = d << 16;
    hi.u = d & 0xffff0000u;
    f32x2 r; r.x = lo.f; r.y = hi.f;
    return r;
}

// ---- weights: wbf (main, kc=k*64+c), wob (offset, kc=k*64+c) — r2 verbatim ----
__global__ __launch_bounds__(256) void k_wconv(const float* __restrict__ w,
                                               const float* __restrict__ ow,
                                               u16* __restrict__ wbf, u16* __restrict__ wob) {
    int i = blockIdx.x * 256 + threadIdx.x;
    const int NW = OC * KCP;
    if (i < NW) {
        int oc = i / KCP, kc = i - oc * KCP;
        float v = 0.f;
        if (kc < KC) { int k = kc >> 6, c = kc & 63; v = w[oc * KC + c * 9 + k]; }  // kc = k*64+c
        wbf[i] = f2bf(v);
    } else {
        int i2 = i - NW;
        if (i2 < 32 * KCP) {
            int oc = i2 / KCP, kc = i2 - oc * KCP;
            float v = 0.f;
            if (oc < 27 && kc < KC) { int k = kc >> 6, c = kc & 63; v = ow[(oc * CI + c) * 9 + k]; }
            wob[i2] = f2bf(v);
        }
    }
}

// ---- transpose v2 (THE one experimental change): LDS-free.
//      thread = one pixel x 8 channels. 8 coalesced dword loads (1KB/wave per
//      c-plane), 4x v_cvt_pk_bf16_f32, one contiguous 16B store. ----
__global__ __launch_bounds__(256) void k_tr(const float* __restrict__ x, u16* __restrict__ xT, int b0) {
    const int t  = threadIdx.x;       // = w
    const int c8 = blockIdx.x;        // channel chunk 0..7
    const int h  = blockIdx.y;
    const int bz = blockIdx.z;
    const float* xp = x + (((size_t)(b0 + bz) * CI + c8 * 8) * HI + h) * WI + t;
    float v[8];
    #pragma unroll
    for (int cc = 0; cc < 8; ++cc) v[cc] = xp[(size_t)cc * (HI * WI)];
    unsigned r[4];
    #pragma unroll
    for (int j = 0; j < 4; ++j)
        asm("v_cvt_pk_bf16_f32 %0, %1, %2" : "=v"(r[j]) : "v"(v[2 * j]), "v"(v[2 * j + 1]));
    *(uint4*)(xT + ((size_t)bz * (HI * WI) + (size_t)h * WI + t) * CI + c8 * 8) =
        make_uint4(r[0], r[1], r[2], r[3]);
}

// ---- offset conv via MFMA — r2 verbatim (incl. XCD swizzle) ----
__global__ __launch_bounds__(256) void k_off(const u16* __restrict__ xT,
                                             const u16* __restrict__ wob,
                                             const float* __restrict__ ob,
                                             float* __restrict__ om) {
    __shared__ u16 s[32 * KCP];
    __shared__ int atab[288];
    __shared__ float red[2][2][64][4];
    const int t = threadIdx.x;
    const unsigned L = (blockIdx.z * gridDim.y + blockIdx.y) * gridDim.x + blockIdx.x;
    const unsigned nwg = gridDim.x * gridDim.y * gridDim.z;
    const unsigned W = (L & 7u) * (nwg >> 3) + (L >> 3);
    const int wo0 = (W & 3u) * 32;
    const int ho  = (W >> 2) & 127u;
    const int bz  = W >> 9;
    const u16* xb = xT + (size_t)bz * (HI * WI * CI);

    for (int p = t; p < 288; p += 256) {
        int px = p / 9, k = p - px * 9;
        int ky = k / 3, kx = k - ky * 3;
        int y  = ho * 2 - 1 + ky;
        int xx = (wo0 + px) * 2 - 1 + kx;
        bool valid = ((unsigned)y < HI) && ((unsigned)xx < WI);
        atab[p] = valid ? (y * WI + xx) * CI : -1;
    }
    __syncthreads();

    #pragma unroll 3
    for (int it = 0; it < 9; ++it) {
        int idx = it * 256 + t;
        int p = idx >> 3, c8 = idx & 7;
        int a = atab[p];
        u16x8 v = {0, 0, 0, 0, 0, 0, 0, 0};
        if (a >= 0) v = *(const u16x8*)(xb + a + c8 * 8);
        int px = p / 9, k = p - px * 9;
        *(u16x8*)&s[px * KCP + k * 64 + c8 * 8] = v;
    }
    __syncthreads();

    const int lane = t & 63, wv = t >> 6;
    const int q = lane >> 4, l15 = lane & 15;
    const int ph = wv & 1, kh = wv >> 1;
    const u16* sp  = &s[(ph * 16 + l15) * KCP + kh * 288 + q * 8];
    const u16* wp0 = wob + l15 * KCP + kh * 288 + q * 8;
    const u16* wp1 = wob + (16 + l15) * KCP + kh * 288 + q * 8;
    f32x4 acc0 = {0.f, 0.f, 0.f, 0.f}, acc1 = {0.f, 0.f, 0.f, 0.f};
    #pragma unroll
    for (int kt = 0; kt < 9; ++kt) {
        bf16x8 a  = *(const bf16x8*)(sp  + kt * 32);
        bf16x8 b0 = *(const bf16x8*)(wp0 + kt * 32);
        bf16x8 b1 = *(const bf16x8*)(wp1 + kt * 32);
        acc0 = __builtin_amdgcn_mfma_f32_16x16x32_bf16(a, b0, acc0, 0, 0, 0);
        acc1 = __builtin_amdgcn_mfma_f32_16x16x32_bf16(a, b1, acc1, 0, 0, 0);
    }
    if (kh == 1) {
        #pragma unroll
        for (int r = 0; r < 4; ++r) { red[ph][0][lane][r] = acc0[r]; red[ph][1][lane][r] = acc1[r]; }
    }
    __syncthreads();
    if (kh == 0) {
        #pragma unroll
        for (int r = 0; r < 4; ++r) { acc0[r] += red[ph][0][lane][r]; acc1[r] += red[ph][1][lane][r]; }
        const int wo = wo0 + ph * 16 + q * 4;
        float bv0 = ob[l15];
        float* o0 = om + ((size_t)(bz * 27 + l15) * HO + ho) * WO + wo;
        *(float4*)o0 = make_float4(acc0[0] + bv0, acc0[1] + bv0, acc0[2] + bv0, acc0[3] + bv0);
        if (l15 < 11) {
            float bv1 = ob[16 + l15];
            float* o1 = om + ((size_t)(bz * 27 + 16 + l15) * HO + ho) * WO + wo;
            *(float4*)o1 = make_float4(acc1[0] + bv1, acc1[1] + bv1, acc1[2] + bv1, acc1[3] + bv1);
        }
    }
}

// ---- main: r2-passing version, byte-identical. TW=32, 512 threads
//      (8 waves = 2 px-halves x 4 oc-groups), 2-deep weight register prefetch. ----
__global__ __launch_bounds__(512, 6) void k_main(const u16* __restrict__ xT,
                                                 const float* __restrict__ om,
                                                 const u16* __restrict__ wbf,
                                                 const float* __restrict__ bias,
                                                 float* __restrict__ out, int b0) {
    __shared__ u16 s[TW * KCP];          // 32*584*2 = 37,376 B
    __shared__ int4   lav[288];          // corner element addrs (pixel*CI)
    __shared__ float4 lwv[288];          // corner weights (incl. mask)

    const int t = threadIdx.x;
    // XCD swizzle: nwg = 4*128*NBz, always % 8 == 0.
    const unsigned L = (blockIdx.z * gridDim.y + blockIdx.y) * gridDim.x + blockIdx.x;
    const unsigned nwg = gridDim.x * gridDim.y * gridDim.z;
    const unsigned W = (L & 7u) * (nwg >> 3) + (L >> 3);
    const int wo0 = (W & 3u) * TW;
    const int ho  = (W >> 2) & 127u;
    const int bz  = W >> 9;
    const int b = b0 + bz;

    if (t < 288) {
        const int p = t;
        const int px_id = p / 9, k = p - px_id * 9;
        const int wo = wo0 + px_id;
        const size_t base = ((size_t)bz * 27) * (HO * WO) + ho * WO + wo;
        float oxv = om[base + (size_t)k * (HO * WO)];
        float oyv = om[base + (size_t)(9 + k) * (HO * WO)];
        float omm = om[base + (size_t)(18 + k) * (HO * WO)];
        float m = 1.f / (1.f + __expf(-omm));
        float py  = oyv + (float)(k / 3) + (float)(ho * 2 - 1);
        float pxf = oxv + (float)(k % 3) + (float)(wo * 2 - 1);
        float fy = floorf(py), fx = floorf(pxf);
        float wy1 = py - fy, wx1 = pxf - fx;
        float wy0 = 1.f - wy1, wx0 = 1.f - wx1;
        int y0 = (int)fy, x0i = (int)fx;
        int y1 = y0 + 1, x1i = x0i + 1;
        bool vy0 = (y0 >= 0) && (y0 < HI), vy1 = (y1 >= 0) && (y1 < HI);
        bool vx0 = (x0i >= 0) && (x0i < WI), vx1 = (x1i >= 0) && (x1i < WI);
        float w00 = (vy0 && vx0) ? wy0 * wx0 * m : 0.f;
        float w01 = (vy0 && vx1) ? wy0 * wx1 * m : 0.f;
        float w10 = (vy1 && vx0) ? wy1 * wx0 * m : 0.f;
        float w11 = (vy1 && vx1) ? wy1 * wx1 * m : 0.f;
        int y0c = (y0 < 0 ? 0 : (y0 > HI-1 ? HI-1 : y0));
        int y1c = (y1 < 0 ? 0 : (y1 > HI-1 ? HI-1 : y1));
        int x0c = (x0i < 0 ? 0 : (x0i > WI-1 ? WI-1 : x0i));
        int x1c = (x1i < 0 ? 0 : (x1i > WI-1 ? WI-1 : x1i));
        lwv[p] = make_float4(w00, w01, w10, w11);
        lav[p] = make_int4((y0c * WI + x0c) * CI, (y0c * WI + x1c) * CI,
                           (y1c * WI + x0c) * CI, (y1c * WI + x1c) * CI);
    }
    __syncthreads();

    // gather: 288 (px,k) pairs x 8 channel-chunks = 2304 items over 512 threads
    const u16* xb = xT + (size_t)bz * (HI * WI * CI);
    auto gb = [&](int i) {
        int p = i >> 3;
        int co = (i & 7) * 8;
        int px_id = p / 9, k = p - px_id * 9;
        float4 wv = lwv[p];
        int4   av = lav[p];
        uint4 da = *(const uint4*)(xb + av.x + co);
        uint4 db = *(const uint4*)(xb + av.y + co);
        uint4 dc = *(const uint4*)(xb + av.z + co);
        uint4 dd = *(const uint4*)(xb + av.w + co);
        const unsigned* ua = (const unsigned*)&da;
        const unsigned* ub = (const unsigned*)&db;
        const unsigned* uc = (const unsigned*)&dc;
        const unsigned* ud = (const unsigned*)&dd;
        union { u16x8 v; unsigned u[4]; } r;
        #pragma unroll
        for (int j2 = 0; j2 < 4; ++j2) {
            f32x2 e = wv.x * unpack2(ua[j2]);
            e += wv.y * unpack2(ub[j2]);
            e += wv.z * unpack2(uc[j2]);
            e += wv.w * unpack2(ud[j2]);
            unsigned pk;
            asm("v_cvt_pk_bf16_f32 %0, %1, %2" : "=v"(pk) : "v"(e.x), "v"(e.y));
            r.u[j2] = pk;
        }
        *(u16x8*)&s[px_id * KCP + k * 64 + co] = r.v;   // kc = k*64 + c, matching wbf
    };
    #pragma unroll 2
    for (int it = 0; it < 4; ++it) gb(it * 512 + t);
    if (t < 256) gb(2048 + t);
    __syncthreads();

    // MFMA phase: 8 waves = 2 pixel-halves (ph) x 4 oc-groups (og); 2-deep B prefetch
    const int lane = t & 63, wv_ = t >> 6;
    const int q = lane >> 4, l15 = lane & 15;
    const int ph = wv_ >> 2, og = wv_ & 3;
    const u16* sp  = &s[(ph * 16 + l15) * KCP + q * 8];
    const int oc0 = og * 32 + l15;
    const int oc1 = oc0 + 16;
    const u16* wp0 = wbf + oc0 * KCP + q * 8;
    const u16* wp1 = wbf + oc1 * KCP + q * 8;
    f32x4 acc0 = {0.f, 0.f, 0.f, 0.f};
    f32x4 acc1 = {0.f, 0.f, 0.f, 0.f};
    bf16x8 b0b[2], b1b[2];
    b0b[0] = *(const bf16x8*)(wp0);
    b1b[0] = *(const bf16x8*)(wp1);
    b0b[1] = *(const bf16x8*)(wp0 + 32);
    b1b[1] = *(const bf16x8*)(wp1 + 32);
    #pragma unroll
    for (int kt = 0; kt < 18; ++kt) {
        bf16x8 a = *(const bf16x8*)(sp + kt * 32);
        acc0 = __builtin_amdgcn_mfma_f32_16x16x32_bf16(a, b0b[kt & 1], acc0, 0, 0, 0);
        acc1 = __builtin_amdgcn_mfma_f32_16x16x32_bf16(a, b1b[kt & 1], acc1, 0, 0, 0);
        if (kt + 2 < 18) {
            b0b[kt & 1] = *(const bf16x8*)(wp0 + (kt + 2) * 32);
            b1b[kt & 1] = *(const bf16x8*)(wp1 + (kt + 2) * 32);
        }
    }
    const float bi0 = bias[oc0], bi1 = bias[oc1];
    const int wo = wo0 + ph * 16 + q * 4;
    float* op0 = out + (((size_t)b * OC + oc0) * HO + ho) * WO + wo;
    float* op1 = out + (((size_t)b * OC + oc1) * HO + ho) * WO + wo;
    *(float4*)op0 = make_float4(acc0[0] + bi0, acc0[1] + bi0, acc0[2] + bi0, acc0[3] + bi0);
    *(float4*)op1 = make_float4(acc1[0] + bi1, acc1[1] + bi1, acc1[2] + bi1, acc1[3] + bi1);
}

extern "C" void kernel_launch(void* const* d_in, const int* in_sizes, int n_in,
                              void* d_out, int out_size, void* d_ws, size_t ws_size,
                              hipStream_t stream) {
    const float* x        = (const float*)d_in[0];
    const float* offset_w = (const float*)d_in[1];
    const float* offset_b = (const float*)d_in[2];
    const float* weight   = (const float*)d_in[3];
    const float* bias     = (const float*)d_in[4];
    float* out = (float*)d_out;

    const size_t xT_full = (size_t)NB * HI * WI * CI * 2;   // 67,108,864
    const size_t om_full = (size_t)NB * 27 * HO * WO * 4;   // 14,155,776
    const size_t xT_b    = (size_t)HI * WI * CI * 2;        //  8,388,608
    const size_t om_b    = (size_t)27 * HO * WO * 4;        //  1,769,472
    const size_t wsz     = (size_t)(OC + 32) * KCP * 2;     //    186,880
    const int nwb = (int)(((OC + 32) * KCP + 255) / 256);

    if (ws_size >= xT_full + om_full + wsz) {
        u16*   xT  = (u16*)d_ws;
        float* om  = (float*)((char*)d_ws + xT_full);
        u16*   wbf = (u16*)((char*)d_ws + xT_full + om_full);
        u16*   wob = wbf + OC * KCP;
        hipLaunchKernelGGL(k_wconv, dim3(nwb), dim3(256), 0, stream, weight, offset_w, wbf, wob);
        hipLaunchKernelGGL(k_tr,   dim3(8, 256, NB), dim3(256), 0, stream, x, xT, 0);
        hipLaunchKernelGGL(k_off,  dim3(4, 128, NB), dim3(256), 0, stream, xT, wob, offset_b, om);
        hipLaunchKernelGGL(k_main, dim3(4, 128, NB), dim3(512), 0, stream, xT, om, wbf, bias, out, 0);
    } else {
        u16*   xT  = (u16*)d_ws;
        float* om  = (float*)((char*)d_ws + xT_b);
        u16*   wbf = (u16*)((char*)d_ws + xT_b + om_b);
        u16*   wob = wbf + OC * KCP;
        hipLaunchKernelGGL(k_wconv, dim3(nwb), dim3(256), 0, stream, weight, offset_w, wbf, wob);
        for (int b = 0; b < NB; ++b) {
            hipLaunchKernelGGL(k_tr,   dim3(8, 256, 1), dim3(256), 0, stream, x, xT, b);
            hipLaunchKernelGGL(k_off,  dim3(4, 128, 1), dim3(256), 0, stream, xT, wob, offset_b, om);
            hipLaunchKernelGGL(k_main, dim3(4, 128, 1), dim3(512), 0, stream, xT, om, wbf, bias, out, b);
        }
    }
}

// Round 7
// 363.434 us; speedup vs baseline: 1.0963x; 1.0963x over previous
//
#include <hip/hip_runtime.h>

typedef unsigned short u16;
typedef __attribute__((ext_vector_type(8))) short bf16x8;
typedef __attribute__((ext_vector_type(8))) unsigned short u16x8;
typedef __attribute__((ext_vector_type(4))) float f32x4;
typedef __attribute__((ext_vector_type(2))) float f32x2;

#define HI 256
#define WI 256
#define CI 64
#define OC 128
#define HO 128
#define WO 128
#define NB 8
#define KC 576
#define KCP 584          // +8 pad to break LDS bank stride
#define TW 32            // k_main pixel tile (r2-passing structure)

static __device__ __forceinline__ u16 f2bf(float f) {   // RNE
    union { float f; unsigned u; } v; v.f = f;
    return (u16)((v.u + 0x7FFFu + ((v.u >> 16) & 1u)) >> 16);
}
// unpack dword of 2 bf16 -> f32x2 (x = low u16 = element j, y = high u16 = element j+1)
static __device__ __forceinline__ f32x2 unpack2(unsigned d) {
    union { unsigned u; float f; } lo, hi;
    lo.u = d << 16;
    hi.u = d & 0xffff0000u;
    f32x2 r; r.x = lo.f; r.y = hi.f;
    return r;
}

// ---- weights: wbf (main, kc=k*64+c), wob (offset, kc=k*64+c) — r2 verbatim ----
__global__ __launch_bounds__(256) void k_wconv(const float* __restrict__ w,
                                               const float* __restrict__ ow,
                                               u16* __restrict__ wbf, u16* __restrict__ wob) {
    int i = blockIdx.x * 256 + threadIdx.x;
    const int NW = OC * KCP;
    if (i < NW) {
        int oc = i / KCP, kc = i - oc * KCP;
        float v = 0.f;
        if (kc < KC) { int k = kc >> 6, c = kc & 63; v = w[oc * KC + c * 9 + k]; }  // kc = k*64+c
        wbf[i] = f2bf(v);
    } else {
        int i2 = i - NW;
        if (i2 < 32 * KCP) {
            int oc = i2 / KCP, kc = i2 - oc * KCP;
            float v = 0.f;
            if (oc < 27 && kc < KC) { int k = kc >> 6, c = kc & 63; v = ow[(oc * CI + c) * 9 + k]; }
            wob[i2] = f2bf(v);
        }
    }
}

// ---- transpose: x[b][c][h][w] fp32 -> xT[bz][h][w][c] bf16 — r2 verbatim
//      (LDS tile; r6 proved the LDS-free variant loses 34us to strided stores) ----
__global__ __launch_bounds__(256) void k_tr(const float* __restrict__ x, u16* __restrict__ xT, int b0) {
    __shared__ u16 tile[64 * 68];
    const int t = threadIdx.x;
    const int w0 = blockIdx.x * 64;
    const int h  = blockIdx.y;
    const int bz = blockIdx.z;
    const float* xp = x + ((size_t)(b0 + bz) * CI) * (HI * WI) + h * WI + w0;
    #pragma unroll
    for (int i = 0; i < 4; ++i) {
        int c = i * 16 + (t >> 4);
        int w = (t & 15) * 4;
        float4 v = *(const float4*)(xp + (size_t)c * (HI * WI) + w);
        tile[(w + 0) * 68 + c] = f2bf(v.x);
        tile[(w + 1) * 68 + c] = f2bf(v.y);
        tile[(w + 2) * 68 + c] = f2bf(v.z);
        tile[(w + 3) * 68 + c] = f2bf(v.w);
    }
    __syncthreads();
    u16* op = xT + (size_t)bz * (HI * WI * CI) + ((size_t)h * WI + w0) * CI;
    #pragma unroll
    for (int j = 0; j < 4; ++j) {
        int w = j * 16 + (t >> 4);
        int c = (t & 15) * 4;
        *(ushort4*)(op + (size_t)w * CI + c) = *(const ushort4*)&tile[w * 68 + c];
    }
}

// ---- offset conv via MFMA — r2 verbatim (incl. XCD swizzle) ----
__global__ __launch_bounds__(256) void k_off(const u16* __restrict__ xT,
                                             const u16* __restrict__ wob,
                                             const float* __restrict__ ob,
                                             float* __restrict__ om) {
    __shared__ u16 s[32 * KCP];
    __shared__ int atab[288];
    __shared__ float red[2][2][64][4];
    const int t = threadIdx.x;
    const unsigned L = (blockIdx.z * gridDim.y + blockIdx.y) * gridDim.x + blockIdx.x;
    const unsigned nwg = gridDim.x * gridDim.y * gridDim.z;
    const unsigned W = (L & 7u) * (nwg >> 3) + (L >> 3);
    const int wo0 = (W & 3u) * 32;
    const int ho  = (W >> 2) & 127u;
    const int bz  = W >> 9;
    const u16* xb = xT + (size_t)bz * (HI * WI * CI);

    for (int p = t; p < 288; p += 256) {
        int px = p / 9, k = p - px * 9;
        int ky = k / 3, kx = k - ky * 3;
        int y  = ho * 2 - 1 + ky;
        int xx = (wo0 + px) * 2 - 1 + kx;
        bool valid = ((unsigned)y < HI) && ((unsigned)xx < WI);
        atab[p] = valid ? (y * WI + xx) * CI : -1;
    }
    __syncthreads();

    #pragma unroll 3
    for (int it = 0; it < 9; ++it) {
        int idx = it * 256 + t;
        int p = idx >> 3, c8 = idx & 7;
        int a = atab[p];
        u16x8 v = {0, 0, 0, 0, 0, 0, 0, 0};
        if (a >= 0) v = *(const u16x8*)(xb + a + c8 * 8);
        int px = p / 9, k = p - px * 9;
        *(u16x8*)&s[px * KCP + k * 64 + c8 * 8] = v;
    }
    __syncthreads();

    const int lane = t & 63, wv = t >> 6;
    const int q = lane >> 4, l15 = lane & 15;
    const int ph = wv & 1, kh = wv >> 1;
    const u16* sp  = &s[(ph * 16 + l15) * KCP + kh * 288 + q * 8];
    const u16* wp0 = wob + l15 * KCP + kh * 288 + q * 8;
    const u16* wp1 = wob + (16 + l15) * KCP + kh * 288 + q * 8;
    f32x4 acc0 = {0.f, 0.f, 0.f, 0.f}, acc1 = {0.f, 0.f, 0.f, 0.f};
    #pragma unroll
    for (int kt = 0; kt < 9; ++kt) {
        bf16x8 a  = *(const bf16x8*)(sp  + kt * 32);
        bf16x8 b0 = *(const bf16x8*)(wp0 + kt * 32);
        bf16x8 b1 = *(const bf16x8*)(wp1 + kt * 32);
        acc0 = __builtin_amdgcn_mfma_f32_16x16x32_bf16(a, b0, acc0, 0, 0, 0);
        acc1 = __builtin_amdgcn_mfma_f32_16x16x32_bf16(a, b1, acc1, 0, 0, 0);
    }
    if (kh == 1) {
        #pragma unroll
        for (int r = 0; r < 4; ++r) { red[ph][0][lane][r] = acc0[r]; red[ph][1][lane][r] = acc1[r]; }
    }
    __syncthreads();
    if (kh == 0) {
        #pragma unroll
        for (int r = 0; r < 4; ++r) { acc0[r] += red[ph][0][lane][r]; acc1[r] += red[ph][1][lane][r]; }
        const int wo = wo0 + ph * 16 + q * 4;
        float bv0 = ob[l15];
        float* o0 = om + ((size_t)(bz * 27 + l15) * HO + ho) * WO + wo;
        *(float4*)o0 = make_float4(acc0[0] + bv0, acc0[1] + bv0, acc0[2] + bv0, acc0[3] + bv0);
        if (l15 < 11) {
            float bv1 = ob[16 + l15];
            float* o1 = om + ((size_t)(bz * 27 + 16 + l15) * HO + ho) * WO + wo;
            *(float4*)o1 = make_float4(acc1[0] + bv1, acc1[1] + bv1, acc1[2] + bv1, acc1[3] + bv1);
        }
    }
}

// ---- main v4: r2 structure, EXPERIMENT = register budget. launch_bounds (512,4)
//      (VGPR cap 40 -> 128), all 16 main-gather corner loads in flight before
//      any consume, 4-deep weight prefetch in the MFMA loop. Same math/layout. ----
__global__ __launch_bounds__(512, 4) void k_main(const u16* __restrict__ xT,
                                                 const float* __restrict__ om,
                                                 const u16* __restrict__ wbf,
                                                 const float* __restrict__ bias,
                                                 float* __restrict__ out, int b0) {
    __shared__ u16 s[TW * KCP];          // 32*584*2 = 37,376 B
    __shared__ int4   lav[288];          // corner element addrs (pixel*CI)
    __shared__ float4 lwv[288];          // corner weights (incl. mask)

    const int t = threadIdx.x;
    // XCD swizzle: nwg = 4*128*NBz, always % 8 == 0.
    const unsigned L = (blockIdx.z * gridDim.y + blockIdx.y) * gridDim.x + blockIdx.x;
    const unsigned nwg = gridDim.x * gridDim.y * gridDim.z;
    const unsigned W = (L & 7u) * (nwg >> 3) + (L >> 3);
    const int wo0 = (W & 3u) * TW;
    const int ho  = (W >> 2) & 127u;
    const int bz  = W >> 9;
    const int b = b0 + bz;

    if (t < 288) {
        const int p = t;
        const int px_id = p / 9, k = p - px_id * 9;
        const int wo = wo0 + px_id;
        const size_t base = ((size_t)bz * 27) * (HO * WO) + ho * WO + wo;
        float oxv = om[base + (size_t)k * (HO * WO)];
        float oyv = om[base + (size_t)(9 + k) * (HO * WO)];
        float omm = om[base + (size_t)(18 + k) * (HO * WO)];
        float m = 1.f / (1.f + __expf(-omm));
        float py  = oyv + (float)(k / 3) + (float)(ho * 2 - 1);
        float pxf = oxv + (float)(k % 3) + (float)(wo * 2 - 1);
        float fy = floorf(py), fx = floorf(pxf);
        float wy1 = py - fy, wx1 = pxf - fx;
        float wy0 = 1.f - wy1, wx0 = 1.f - wx1;
        int y0 = (int)fy, x0i = (int)fx;
        int y1 = y0 + 1, x1i = x0i + 1;
        bool vy0 = (y0 >= 0) && (y0 < HI), vy1 = (y1 >= 0) && (y1 < HI);
        bool vx0 = (x0i >= 0) && (x0i < WI), vx1 = (x1i >= 0) && (x1i < WI);
        float w00 = (vy0 && vx0) ? wy0 * wx0 * m : 0.f;
        float w01 = (vy0 && vx1) ? wy0 * wx1 * m : 0.f;
        float w10 = (vy1 && vx0) ? wy1 * wx0 * m : 0.f;
        float w11 = (vy1 && vx1) ? wy1 * wx1 * m : 0.f;
        int y0c = (y0 < 0 ? 0 : (y0 > HI-1 ? HI-1 : y0));
        int y1c = (y1 < 0 ? 0 : (y1 > HI-1 ? HI-1 : y1));
        int x0c = (x0i < 0 ? 0 : (x0i > WI-1 ? WI-1 : x0i));
        int x1c = (x1i < 0 ? 0 : (x1i > WI-1 ? WI-1 : x1i));
        lwv[p] = make_float4(w00, w01, w10, w11);
        lav[p] = make_int4((y0c * WI + x0c) * CI, (y0c * WI + x1c) * CI,
                           (y1c * WI + x0c) * CI, (y1c * WI + x1c) * CI);
    }
    __syncthreads();

    // gather: 2304 items over 512 threads. Main 4 iterations: issue ALL 16 corner
    // loads before consuming any (deep memory parallelism); tail item after.
    const u16* xb = xT + (size_t)bz * (HI * WI * CI);
    {
        uint4 da[4], db[4], dc[4], dd[4];
        float4 wv[4];
        #pragma unroll
        for (int it = 0; it < 4; ++it) {
            int i = it * 512 + t;
            int p = i >> 3;
            int co = (i & 7) * 8;
            wv[it] = lwv[p];
            int4 av = lav[p];
            da[it] = *(const uint4*)(xb + av.x + co);
            db[it] = *(const uint4*)(xb + av.y + co);
            dc[it] = *(const uint4*)(xb + av.z + co);
            dd[it] = *(const uint4*)(xb + av.w + co);
        }
        #pragma unroll
        for (int it = 0; it < 4; ++it) {
            int i = it * 512 + t;
            int p = i >> 3;
            int co = (i & 7) * 8;
            int px_id = p / 9, k = p - px_id * 9;
            const unsigned* ua = (const unsigned*)&da[it];
            const unsigned* ub = (const unsigned*)&db[it];
            const unsigned* uc = (const unsigned*)&dc[it];
            const unsigned* ud = (const unsigned*)&dd[it];
            union { u16x8 v; unsigned u[4]; } r;
            #pragma unroll
            for (int j2 = 0; j2 < 4; ++j2) {
                f32x2 e = wv[it].x * unpack2(ua[j2]);
                e += wv[it].y * unpack2(ub[j2]);
                e += wv[it].z * unpack2(uc[j2]);
                e += wv[it].w * unpack2(ud[j2]);
                unsigned pk;
                asm("v_cvt_pk_bf16_f32 %0, %1, %2" : "=v"(pk) : "v"(e.x), "v"(e.y));
                r.u[j2] = pk;
            }
            *(u16x8*)&s[px_id * KCP + k * 64 + co] = r.v;   // kc = k*64 + c
        }
    }
    if (t < 256) {
        int i = 2048 + t;
        int p = i >> 3;
        int co = (i & 7) * 8;
        int px_id = p / 9, k = p - px_id * 9;
        float4 wv = lwv[p];
        int4   av = lav[p];
        uint4 da = *(const uint4*)(xb + av.x + co);
        uint4 db = *(const uint4*)(xb + av.y + co);
        uint4 dc = *(const uint4*)(xb + av.z + co);
        uint4 dd = *(const uint4*)(xb + av.w + co);
        const unsigned* ua = (const unsigned*)&da;
        const unsigned* ub = (const unsigned*)&db;
        const unsigned* uc = (const unsigned*)&dc;
        const unsigned* ud = (const unsigned*)&dd;
        union { u16x8 v; unsigned u[4]; } r;
        #pragma unroll
        for (int j2 = 0; j2 < 4; ++j2) {
            f32x2 e = wv.x * unpack2(ua[j2]);
            e += wv.y * unpack2(ub[j2]);
            e += wv.z * unpack2(uc[j2]);
            e += wv.w * unpack2(ud[j2]);
            unsigned pk;
            asm("v_cvt_pk_bf16_f32 %0, %1, %2" : "=v"(pk) : "v"(e.x), "v"(e.y));
            r.u[j2] = pk;
        }
        *(u16x8*)&s[px_id * KCP + k * 64 + co] = r.v;
    }
    __syncthreads();

    // MFMA phase: 8 waves = 2 pixel-halves (ph) x 4 oc-groups (og); 4-deep B prefetch
    const int lane = t & 63, wv_ = t >> 6;
    const int q = lane >> 4, l15 = lane & 15;
    const int ph = wv_ >> 2, og = wv_ & 3;
    const u16* sp  = &s[(ph * 16 + l15) * KCP + q * 8];
    const int oc0 = og * 32 + l15;
    const int oc1 = oc0 + 16;
    const u16* wp0 = wbf + oc0 * KCP + q * 8;
    const u16* wp1 = wbf + oc1 * KCP + q * 8;
    f32x4 acc0 = {0.f, 0.f, 0.f, 0.f};
    f32x4 acc1 = {0.f, 0.f, 0.f, 0.f};
    bf16x8 b0b[4], b1b[4];
    #pragma unroll
    for (int d = 0; d < 4; ++d) {
        b0b[d] = *(const bf16x8*)(wp0 + d * 32);
        b1b[d] = *(const bf16x8*)(wp1 + d * 32);
    }
    #pragma unroll
    for (int kt = 0; kt < 18; ++kt) {
        bf16x8 a = *(const bf16x8*)(sp + kt * 32);
        acc0 = __builtin_amdgcn_mfma_f32_16x16x32_bf16(a, b0b[kt & 3], acc0, 0, 0, 0);
        acc1 = __builtin_amdgcn_mfma_f32_16x16x32_bf16(a, b1b[kt & 3], acc1, 0, 0, 0);
        if (kt + 4 < 18) {
            b0b[kt & 3] = *(const bf16x8*)(wp0 + (kt + 4) * 32);
            b1b[kt & 3] = *(const bf16x8*)(wp1 + (kt + 4) * 32);
        }
    }
    const float bi0 = bias[oc0], bi1 = bias[oc1];
    const int wo = wo0 + ph * 16 + q * 4;
    float* op0 = out + (((size_t)b * OC + oc0) * HO + ho) * WO + wo;
    float* op1 = out + (((size_t)b * OC + oc1) * HO + ho) * WO + wo;
    *(float4*)op0 = make_float4(acc0[0] + bi0, acc0[1] + bi0, acc0[2] + bi0, acc0[3] + bi0);
    *(float4*)op1 = make_float4(acc1[0] + bi1, acc1[1] + bi1, acc1[2] + bi1, acc1[3] + bi1);
}

extern "C" void kernel_launch(void* const* d_in, const int* in_sizes, int n_in,
                              void* d_out, int out_size, void* d_ws, size_t ws_size,
                              hipStream_t stream) {
    const float* x        = (const float*)d_in[0];
    const float* offset_w = (const float*)d_in[1];
    const float* offset_b = (const float*)d_in[2];
    const float* weight   = (const float*)d_in[3];
    const float* bias     = (const float*)d_in[4];
    float* out = (float*)d_out;

    const size_t xT_full = (size_t)NB * HI * WI * CI * 2;   // 67,108,864
    const size_t om_full = (size_t)NB * 27 * HO * WO * 4;   // 14,155,776
    const size_t xT_b    = (size_t)HI * WI * CI * 2;        //  8,388,608
    const size_t om_b    = (size_t)27 * HO * WO * 4;        //  1,769,472
    const size_t wsz     = (size_t)(OC + 32) * KCP * 2;     //    186,880
    const int nwb = (int)(((OC + 32) * KCP + 255) / 256);

    if (ws_size >= xT_full + om_full + wsz) {
        u16*   xT  = (u16*)d_ws;
        float* om  = (float*)((char*)d_ws + xT_full);
        u16*   wbf = (u16*)((char*)d_ws + xT_full + om_full);
        u16*   wob = wbf + OC * KCP;
        hipLaunchKernelGGL(k_wconv, dim3(nwb), dim3(256), 0, stream, weight, offset_w, wbf, wob);
        hipLaunchKernelGGL(k_tr,   dim3(4, 256, NB), dim3(256), 0, stream, x, xT, 0);
        hipLaunchKernelGGL(k_off,  dim3(4, 128, NB), dim3(256), 0, stream, xT, wob, offset_b, om);
        hipLaunchKernelGGL(k_main, dim3(4, 128, NB), dim3(512), 0, stream, xT, om, wbf, bias, out, 0);
    } else {
        u16*   xT  = (u16*)d_ws;
        float* om  = (float*)((char*)d_ws + xT_b);
        u16*   wbf = (u16*)((char*)d_ws + xT_b + om_b);
        u16*   wob = wbf + OC * KCP;
        hipLaunchKernelGGL(k_wconv, dim3(nwb), dim3(256), 0, stream, weight, offset_w, wbf, wob);
        for (int b = 0; b < NB; ++b) {
            hipLaunchKernelGGL(k_tr,   dim3(4, 256, 1), dim3(256), 0, stream, x, xT, b);
            hipLaunchKernelGGL(k_off,  dim3(4, 128, 1), dim3(256), 0, stream, xT, wob, offset_b, om);
            hipLaunchKernelGGL(k_main, dim3(4, 128, 1), dim3(512), 0, stream, xT, om, wbf, bias, out, b);
        }
    }
}